// Round 1
// baseline (469.367 us; speedup 1.0000x reference)
//
#include <hip/hip_runtime.h>
#include <hip/hip_bf16.h>

// Additive attention scores: scores[b,t] = sum_u tanh((source@W1)[b,u] + (target@W2)[b,t,u]) * a[u]
// B=64 T=8192 D=256 U=128. Memory-bound: 537MB target read dominates.
// Strategy: bf16 MFMA (16x16x32) for target@W2, fp32 everything else, fused epilogue.

#define B_ 64
#define T_ 8192
#define D_ 256
#define U_ 128

typedef __attribute__((ext_vector_type(8))) short bf16x8;
typedef __attribute__((ext_vector_type(4))) float f32x4;

__device__ __forceinline__ short f2bf(float f) {
    unsigned u = __builtin_bit_cast(unsigned, f);
    u += 0x7fffu + ((u >> 16) & 1u);   // round-to-nearest-even
    return (short)(u >> 16);
}

__device__ __forceinline__ float fast_tanh(float x) {
    // tanh(x) = 1 - 2/(e^{2x}+1); exact at +/-inf, ~1ulp via v_exp/v_rcp
    float e = __expf(2.0f * x);
    return 1.0f - 2.0f * __builtin_amdgcn_rcpf(e + 1.0f);
}

// W2 staged transposed [U][D] bf16. Stride 264 (=256+8 pad): row stride 528B
// -> ds_read_b128 phases are uniform 2-way on banks (free per m136).
#define LDS_STRIDE 264

__global__ __launch_bounds__(512, 4) void additive_attn_kernel(
        const float* __restrict__ target,
        const float* __restrict__ source,
        const float* __restrict__ W1,
        const float* __restrict__ W2,
        const float* __restrict__ attn,
        float* __restrict__ out) {
    __shared__ __attribute__((aligned(16))) short lds_w2[U_ * LDS_STRIDE];
    __shared__ float lds_red[512];
    __shared__ float lds_s[U_];

    const int tid = threadIdx.x;
    const int bx  = blockIdx.x;
    const int b   = bx >> 4;           // 16 blocks per batch element
    const int tb  = (bx & 15) << 9;    // 512 rows of T per block

    // --- stage W2: fp32 [D][U] -> bf16 LDS [U][D] (transposed) ---
    for (int idx = tid; idx < D_ * U_; idx += 512) {
        int d = idx >> 7;            // since U_ == 128
        int u = idx & (U_ - 1);
        lds_w2[u * LDS_STRIDE + d] = f2bf(W2[idx]);
    }

    // --- s[u] = (source[b] @ W1)[u] in fp32, 4-way split over D ---
    {
        const float* src = source + b * D_;
        int u    = tid & (U_ - 1);
        int part = tid >> 7;         // 0..3
        float acc = 0.f;
        #pragma unroll 8
        for (int d = part * 64; d < part * 64 + 64; ++d)
            acc = fmaf(src[d], W1[(size_t)d * U_ + u], acc);
        lds_red[tid] = acc;
    }
    __syncthreads();
    if (tid < U_)
        lds_s[tid] = lds_red[tid] + lds_red[tid + 128] + lds_red[tid + 256] + lds_red[tid + 384];
    __syncthreads();

    const int lane = tid & 63;
    const int wave = tid >> 6;   // 0..7 (8 waves)
    const int c = lane & 15;     // A-row / B-col / C-col selector
    const int g = lane >> 4;     // 0..3, k-group / C-row group

    // per-lane epilogue constants: u = 16*j + c
    float s_u[8], a_u[8];
    #pragma unroll
    for (int j = 0; j < 8; ++j) {
        s_u[j] = lds_s[16 * j + c];
        a_u[j] = attn[16 * j + c];
    }

    const float* tgt  = target + ((size_t)b * T_ + tb) * D_;
    float*       outp = out + (size_t)b * T_ + tb;

    for (int it = 0; it < 4; ++it) {
        const int row0 = it * 128 + wave * 16;   // 16 rows per wave per iter
        const float* A = tgt + (size_t)(row0 + c) * D_ + g * 8;

        f32x4 acc[8];
        #pragma unroll
        for (int j = 0; j < 8; ++j) acc[j] = (f32x4){0.f, 0.f, 0.f, 0.f};

        #pragma unroll
        for (int s = 0; s < 8; ++s) {
            // A frag: row = c, k = 32s + 8g + i  (8 consecutive fp32 = 32B/lane)
            const float4 lo = *(const float4*)(A + s * 32);
            const float4 hi = *(const float4*)(A + s * 32 + 4);
            bf16x8 af;
            af[0] = f2bf(lo.x); af[1] = f2bf(lo.y);
            af[2] = f2bf(lo.z); af[3] = f2bf(lo.w);
            af[4] = f2bf(hi.x); af[5] = f2bf(hi.y);
            af[6] = f2bf(hi.z); af[7] = f2bf(hi.w);
            const int kb = s * 32 + g * 8;
            #pragma unroll
            for (int j = 0; j < 8; ++j) {
                // B frag: col = 16j + c, k = 32s + 8g + i (contiguous in LDS row)
                bf16x8 bfrag = *(const bf16x8*)(&lds_w2[(16 * j + c) * LDS_STRIDE + kb]);
                acc[j] = __builtin_amdgcn_mfma_f32_16x16x32_bf16(af, bfrag, acc[j], 0, 0, 0);
            }
        }

        // epilogue: C layout col = c, row = 4g + r. scores = sum_u tanh(t+s)*a
        #pragma unroll
        for (int r = 0; r < 4; ++r) {
            float sum = 0.f;
            #pragma unroll
            for (int j = 0; j < 8; ++j)
                sum += fast_tanh(acc[j][r] + s_u[j]) * a_u[j];
            sum += __shfl_xor(sum, 1);
            sum += __shfl_xor(sum, 2);
            sum += __shfl_xor(sum, 4);
            sum += __shfl_xor(sum, 8);
            if (c == 0) outp[row0 + g * 4 + r] = sum;
        }
    }
}

extern "C" void kernel_launch(void* const* d_in, const int* in_sizes, int n_in,
                              void* d_out, int out_size, void* d_ws, size_t ws_size,
                              hipStream_t stream) {
    const float* target = (const float*)d_in[0];
    const float* source = (const float*)d_in[1];
    const float* W1     = (const float*)d_in[2];
    const float* W2     = (const float*)d_in[3];
    const float* attn   = (const float*)d_in[4];
    float* out = (float*)d_out;

    dim3 grid(B_ * (T_ / 512));   // 1024 blocks
    dim3 block(512);
    hipLaunchKernelGGL(additive_attn_kernel, grid, block, 0, stream,
                       target, source, W1, W2, attn, out);
}

// Round 2
// 112.795 us; speedup vs baseline: 4.1612x; 4.1612x over previous
//
#include <hip/hip_runtime.h>
#include <hip/hip_bf16.h>

// scores[b,t] = sum_u tanh((source@W1)[b,u] + (target@W2)[b,t,u]) * a[u]
// B=64 T=8192 D=256 U=128. Memory-bound: 537MB target read. bf16 MFMA for target@W2.
// Round 2: kill register spill (round 1: VGPR=64, 426MB scratch writes). Batched
// register double-buffer (4xfloat4 per batch), swapped MFMA operands so the
// epilogue is lane-local (s/a from LDS broadcast), cvt_pk bf16 conversion.

#define B_ 64
#define T_ 8192
#define D_ 256
#define U_ 128
#define LDSW 264   // bf16 elems/row; 528B = 33 16B-slots (odd) -> uniform bank spread

typedef __attribute__((ext_vector_type(8))) short bf16x8;
typedef __attribute__((ext_vector_type(4))) float f32x4;

__device__ __forceinline__ short f2bf(float f) {
    unsigned u = __builtin_bit_cast(unsigned, f);
    u += 0x7fffu + ((u >> 16) & 1u);   // RTNE
    return (short)(u >> 16);
}

__device__ __forceinline__ float fast_tanh(float x) {
    // tanh(x) = 1 - 2/(e^{2x}+1); correct at +/-inf
    float e = __expf(2.0f * x);
    return 1.0f - 2.0f * __builtin_amdgcn_rcpf(e + 1.0f);
}

// pack 8 fp32 -> bf16x8 via v_cvt_pk_bf16_f32 (RTNE), 4 instrs
__device__ __forceinline__ bf16x8 cvt8(const float4& a, const float4& b) {
    union { __hip_bfloat162 h[4]; bf16x8 v; } u;
    u.h[0] = __float22bfloat162_rn(make_float2(a.x, a.y));
    u.h[1] = __float22bfloat162_rn(make_float2(a.z, a.w));
    u.h[2] = __float22bfloat162_rn(make_float2(b.x, b.y));
    u.h[3] = __float22bfloat162_rn(make_float2(b.z, b.w));
    return u.v;
}

__global__ __launch_bounds__(512, 4) void additive_attn_kernel(
        const float* __restrict__ target,
        const float* __restrict__ source,
        const float* __restrict__ W1,
        const float* __restrict__ W2,
        const float* __restrict__ attn,
        float* __restrict__ out) {
    __shared__ __attribute__((aligned(16))) short lds_w2[U_ * LDSW]; // [u][d] bf16
    __shared__ float  lds_red[512];
    __shared__ float2 lds_sa[U_];   // {s_u, a_u}

    const int tid = threadIdx.x;
    const int bx  = blockIdx.x;
    const int b   = bx >> 4;           // 16 blocks per batch element
    const int tb  = (bx & 15) << 9;    // 512 rows of T per block

    const int lane = tid & 63;
    const int wave = tid >> 6;   // 0..7
    const int c = lane & 15;
    const int g = lane >> 4;

    const float* tgt  = target + ((size_t)b * T_ + tb) * D_;
    float*       outp = out + (size_t)b * T_ + tb;
    // per-lane A base: row = it*128 + wave*16 + c, k-offset g*8
    const float* Abase = tgt + (size_t)(wave * 16 + c) * D_ + g * 8;

    float4 xa0, xa1, xa2, xa3, xb0, xb1, xb2, xb3;

#define LOADB(X0, X1, X2, X3, BI) do {                                        \
    const float* p_ = Abase + (size_t)((BI) >> 2) * (128 * D_) + ((BI) & 3) * 64; \
    X0 = *(const float4*)(p_);      X1 = *(const float4*)(p_ + 4);            \
    X2 = *(const float4*)(p_ + 32); X3 = *(const float4*)(p_ + 36);           \
} while (0)

    // issue first A batch before staging (overlaps HBM latency with prologue)
    LOADB(xa0, xa1, xa2, xa3, 0);

    // --- stage W2: fp32 [D][U] -> bf16 LDS [u][d], b128 writes, conflict-free ---
    {
        const int u    = tid & (U_ - 1);
        const int dblk = (tid >> 7) << 6;    // 0,64,128,192
        #pragma unroll
        for (int w = 0; w < 8; ++w) {
            const int d0 = dblk + w * 8;
            bf16x8 v;
            #pragma unroll
            for (int i = 0; i < 8; ++i)
                v[i] = f2bf(W2[(size_t)(d0 + i) * U_ + u]);
            *(bf16x8*)&lds_w2[u * LDSW + d0] = v;
        }
    }

    // --- s[u] = (source[b] @ W1)[u], 4-way D split ---
    {
        const float* src = source + b * D_;
        const int u    = tid & (U_ - 1);
        const int part = tid >> 7;
        float acc = 0.f;
        #pragma unroll 8
        for (int d = part * 64; d < part * 64 + 64; ++d)
            acc = fmaf(src[d], W1[(size_t)d * U_ + u], acc);
        lds_red[tid] = acc;
    }
    __syncthreads();
    if (tid < U_)
        lds_sa[tid] = make_float2(
            lds_red[tid] + lds_red[tid + 128] + lds_red[tid + 256] + lds_red[tid + 384],
            attn[tid]);
    __syncthreads();

    f32x4 acc[8];
    #pragma unroll
    for (int j = 0; j < 8; ++j) acc[j] = (f32x4){0.f, 0.f, 0.f, 0.f};

    // MFMA with SWAPPED operands: A-op = W2 frag (m index = u-within-tile),
    // B-op = target frag (n index = target row c). D[m=4g+r][n=c].
#define COMP(X0, X1, X2, X3, Q) do {                                          \
    bf16x8 af0 = cvt8(X0, X1);                                                \
    bf16x8 af1 = cvt8(X2, X3);                                                \
    const int kb_ = (Q) * 64 + g * 8;                                         \
    _Pragma("unroll")                                                         \
    for (int j = 0; j < 8; ++j) {                                             \
        bf16x8 w0 = *(const bf16x8*)&lds_w2[(16 * j + c) * LDSW + kb_];       \
        acc[j] = __builtin_amdgcn_mfma_f32_16x16x32_bf16(w0, af0, acc[j], 0, 0, 0); \
        bf16x8 w1 = *(const bf16x8*)&lds_w2[(16 * j + c) * LDSW + kb_ + 32];  \
        acc[j] = __builtin_amdgcn_mfma_f32_16x16x32_bf16(w1, af1, acc[j], 0, 0, 0); \
    }                                                                         \
} while (0)

    // epilogue: lane (c,g) holds t[row0+c][u=16j+4g+r] in acc[j][r]
#define EPI(IT) do {                                                          \
    float sc = 0.f;                                                           \
    _Pragma("unroll")                                                         \
    for (int j = 0; j < 8; ++j) {                                             \
        float4 sa01 = *(const float4*)&lds_sa[16 * j + 4 * g];                \
        float4 sa23 = *(const float4*)&lds_sa[16 * j + 4 * g + 2];            \
        sc += fast_tanh(acc[j][0] + sa01.x) * sa01.y;                         \
        sc += fast_tanh(acc[j][1] + sa01.z) * sa01.w;                         \
        sc += fast_tanh(acc[j][2] + sa23.x) * sa23.y;                         \
        sc += fast_tanh(acc[j][3] + sa23.z) * sa23.w;                         \
        acc[j] = (f32x4){0.f, 0.f, 0.f, 0.f};                                 \
    }                                                                         \
    sc += __shfl_xor(sc, 16);                                                 \
    sc += __shfl_xor(sc, 32);                                                 \
    if (lane < 16) outp[(IT) * 128 + wave * 16 + lane] = sc;                  \
} while (0)

    // 16 batches = 4 row-tiles x 4 k-quarters; register double-buffer keeps
    // exactly one batch (4 dwordx4/lane) in flight during compute.
    #pragma unroll
    for (int bi = 0; bi < 16; ++bi) {
        if ((bi & 1) == 0) {
            if (bi < 15) LOADB(xb0, xb1, xb2, xb3, bi + 1);
            COMP(xa0, xa1, xa2, xa3, bi & 3);
        } else {
            if (bi < 15) LOADB(xa0, xa1, xa2, xa3, bi + 1);
            COMP(xb0, xb1, xb2, xb3, bi & 3);
        }
        if ((bi & 3) == 3) EPI(bi >> 2);
    }

#undef LOADB
#undef COMP
#undef EPI
}

extern "C" void kernel_launch(void* const* d_in, const int* in_sizes, int n_in,
                              void* d_out, int out_size, void* d_ws, size_t ws_size,
                              hipStream_t stream) {
    const float* target = (const float*)d_in[0];
    const float* source = (const float*)d_in[1];
    const float* W1     = (const float*)d_in[2];
    const float* W2     = (const float*)d_in[3];
    const float* attn   = (const float*)d_in[4];
    float* out = (float*)d_out;

    dim3 grid(B_ * (T_ / 512));   // 1024 blocks
    dim3 block(512);
    hipLaunchKernelGGL(additive_attn_kernel, grid, block, 0, stream,
                       target, source, W1, W2, attn, out);
}

// Round 3
// 108.035 us; speedup vs baseline: 4.3446x; 1.0441x over previous
//
#include <hip/hip_runtime.h>
#include <hip/hip_bf16.h>

// scores[b,t] = sum_u tanh((source@W1)[b,u] + (target@W2)[b,t,u]) * a[u]
// B=64 T=8192 D=256 U=128. Memory-bound: 537MB target read at 6.3TB/s => ~86us floor.
// Round 3: persistent-shape grid (512 blocks = 2/CU exactly, 1024 rows each) so the
// W2-staging prologue runs once per CU-slot and there is no second dispatch round;
// 3-deep register pipeline (8KB/wave in flight) to hold HBM saturation across EPI.

#define B_ 64
#define T_ 8192
#define D_ 256
#define U_ 128
#define LDSW 264   // bf16 elems/row; 528B row stride -> conflict-free b128 frag reads

typedef __attribute__((ext_vector_type(8))) short bf16x8;
typedef __attribute__((ext_vector_type(4))) float f32x4;

__device__ __forceinline__ short f2bf(float f) {
    unsigned u = __builtin_bit_cast(unsigned, f);
    u += 0x7fffu + ((u >> 16) & 1u);   // RTNE
    return (short)(u >> 16);
}

__device__ __forceinline__ float fast_tanh(float x) {
    float e = __expf(2.0f * x);        // v_exp_f32 path
    return 1.0f - 2.0f * __builtin_amdgcn_rcpf(e + 1.0f);
}

__device__ __forceinline__ bf16x8 cvt8(const float4& a, const float4& b) {
    union { __hip_bfloat162 h[4]; bf16x8 v; } u;
    u.h[0] = __float22bfloat162_rn(make_float2(a.x, a.y));
    u.h[1] = __float22bfloat162_rn(make_float2(a.z, a.w));
    u.h[2] = __float22bfloat162_rn(make_float2(b.x, b.y));
    u.h[3] = __float22bfloat162_rn(make_float2(b.z, b.w));
    return u.v;
}

__global__ __launch_bounds__(512, 4) void additive_attn_kernel(
        const float* __restrict__ target,
        const float* __restrict__ source,
        const float* __restrict__ W1,
        const float* __restrict__ W2,
        const float* __restrict__ attn,
        float* __restrict__ out) {
    __shared__ __attribute__((aligned(16))) short lds_w2[U_ * LDSW]; // [u][d] bf16
    __shared__ float  lds_red[512];
    __shared__ float2 lds_sa[U_];   // {s_u, a_u}

    const int tid = threadIdx.x;
    const int bx  = blockIdx.x;
    const int b   = bx >> 3;            // 8 blocks per batch element
    const int tb  = (bx & 7) << 10;     // 1024 rows per block

    const int lane = tid & 63;
    const int wave = tid >> 6;   // 0..7
    const int c = lane & 15;
    const int g = lane >> 4;

    const float* tgt  = target + ((size_t)b * T_ + tb) * D_;
    float*       outp = out + (size_t)b * T_ + tb;
    const float* Abase = tgt + (size_t)(wave * 16 + c) * D_ + g * 8;

    // 3 payload sets (4 x float4 each): 48 VGPRs
    float4 p0, p1, p2, p3, q0, q1, q2, q3, r0, r1, r2, r3;

#define LOADB(X0, X1, X2, X3, BI) do {                                        \
    const float* p_ = Abase + (size_t)((BI) >> 2) * (128 * D_) + ((BI) & 3) * 64; \
    X0 = *(const float4*)(p_);      X1 = *(const float4*)(p_ + 4);            \
    X2 = *(const float4*)(p_ + 32); X3 = *(const float4*)(p_ + 36);           \
} while (0)

    // prime 2 batches before the prologue (8KB/wave in flight over staging)
    LOADB(p0, p1, p2, p3, 0);
    LOADB(q0, q1, q2, q3, 1);

    // --- stage W2: fp32 [D][U] -> bf16 LDS [u][d], b128 writes ---
    {
        const int u    = tid & (U_ - 1);
        const int dblk = (tid >> 7) << 6;    // 0,64,128,192
        #pragma unroll
        for (int w = 0; w < 8; ++w) {
            const int d0 = dblk + w * 8;
            bf16x8 v;
            #pragma unroll
            for (int i = 0; i < 8; ++i)
                v[i] = f2bf(W2[(size_t)(d0 + i) * U_ + u]);
            *(bf16x8*)&lds_w2[u * LDSW + d0] = v;
        }
    }

    // --- s[u] = (source[b] @ W1)[u], 4-way D split ---
    {
        const float* src = source + b * D_;
        const int u    = tid & (U_ - 1);
        const int part = tid >> 7;
        float acc = 0.f;
        #pragma unroll 8
        for (int d = part * 64; d < part * 64 + 64; ++d)
            acc = fmaf(src[d], W1[(size_t)d * U_ + u], acc);
        lds_red[tid] = acc;
    }
    __syncthreads();
    if (tid < U_)
        lds_sa[tid] = make_float2(
            lds_red[tid] + lds_red[tid + 128] + lds_red[tid + 256] + lds_red[tid + 384],
            attn[tid]);
    __syncthreads();

    f32x4 acc[8];
    #pragma unroll
    for (int j = 0; j < 8; ++j) acc[j] = (f32x4){0.f, 0.f, 0.f, 0.f};

    // swapped operands: A-op = W2 frag (m = u-in-tile), B-op = target (n = row c)
#define COMP(X0, X1, X2, X3, Q) do {                                          \
    bf16x8 af0 = cvt8(X0, X1);                                                \
    bf16x8 af1 = cvt8(X2, X3);                                                \
    const int kb_ = (Q) * 64 + g * 8;                                         \
    _Pragma("unroll")                                                         \
    for (int j = 0; j < 8; ++j) {                                             \
        bf16x8 w0 = *(const bf16x8*)&lds_w2[(16 * j + c) * LDSW + kb_];       \
        acc[j] = __builtin_amdgcn_mfma_f32_16x16x32_bf16(w0, af0, acc[j], 0, 0, 0); \
        bf16x8 w1 = *(const bf16x8*)&lds_w2[(16 * j + c) * LDSW + kb_ + 32];  \
        acc[j] = __builtin_amdgcn_mfma_f32_16x16x32_bf16(w1, af1, acc[j], 0, 0, 0); \
    }                                                                         \
} while (0)

    // lane (c,g) holds t[row][u=16j+4g+r] in acc[j][r]; row = rt*128+wave*16+c
#define EPI(IT) do {                                                          \
    float sc = 0.f;                                                           \
    _Pragma("unroll")                                                         \
    for (int j = 0; j < 8; ++j) {                                             \
        float4 sa01 = *(const float4*)&lds_sa[16 * j + 4 * g];                \
        float4 sa23 = *(const float4*)&lds_sa[16 * j + 4 * g + 2];            \
        sc += fast_tanh(acc[j][0] + sa01.x) * sa01.y;                         \
        sc += fast_tanh(acc[j][1] + sa01.z) * sa01.w;                         \
        sc += fast_tanh(acc[j][2] + sa23.x) * sa23.y;                         \
        sc += fast_tanh(acc[j][3] + sa23.z) * sa23.w;                         \
        acc[j] = (f32x4){0.f, 0.f, 0.f, 0.f};                                 \
    }                                                                         \
    sc += __shfl_xor(sc, 16);                                                 \
    sc += __shfl_xor(sc, 32);                                                 \
    if (lane < 16) outp[(IT) * 128 + wave * 16 + lane] = sc;                  \
} while (0)

    // 32 batches = 8 row-tiles x 4 k-quarters; 3-deep pipeline (2 batches in
    // flight during each COMP). Fully unrolled -> all reg indices static.
    #pragma unroll
    for (int bi = 0; bi < 32; ++bi) {
        if (bi % 3 == 0) {
            if (bi < 30) LOADB(r0, r1, r2, r3, bi + 2);
            COMP(p0, p1, p2, p3, bi & 3);
        } else if (bi % 3 == 1) {
            if (bi < 30) LOADB(p0, p1, p2, p3, bi + 2);
            COMP(q0, q1, q2, q3, bi & 3);
        } else {
            if (bi < 30) LOADB(q0, q1, q2, q3, bi + 2);
            COMP(r0, r1, r2, r3, bi & 3);
        }
        if ((bi & 3) == 3) EPI(bi >> 2);
    }

#undef LOADB
#undef COMP
#undef EPI
}

extern "C" void kernel_launch(void* const* d_in, const int* in_sizes, int n_in,
                              void* d_out, int out_size, void* d_ws, size_t ws_size,
                              hipStream_t stream) {
    const float* target = (const float*)d_in[0];
    const float* source = (const float*)d_in[1];
    const float* W1     = (const float*)d_in[2];
    const float* W2     = (const float*)d_in[3];
    const float* attn   = (const float*)d_in[4];
    float* out = (float*)d_out;

    dim3 grid(B_ * (T_ / 1024));   // 512 blocks = 2 per CU, one dispatch round
    dim3 block(512);
    hipLaunchKernelGGL(additive_attn_kernel, grid, block, 0, stream,
                       target, source, W1, W2, attn, out);
}

// Round 4
// 107.855 us; speedup vs baseline: 4.3518x; 1.0017x over previous
//
#include <hip/hip_runtime.h>
#include <hip/hip_bf16.h>

// scores[b,t] = sum_u tanh((source@W1)[b,u] + (target@W2)[b,t,u]) * a[u]
// B=64 T=8192 D=256 U=128. Memory-bound: 537MB target read at ~6.3TB/s => ~86us floor.
// Round 4: pin regalloc at 4 waves/EU (128 VGPR) via amdgpu_waves_per_eu(4,4).
// Round 1 proved the allocator picks VGPR=64 + massive scratch spill under
// launch_bounds(512,4) alone (WRITE_SIZE 416MB vs 2MB ideal); rounds 2/3 likely
// still spill the pipeline buffers. Same structure as round 3 otherwise.

#define B_ 64
#define T_ 8192
#define D_ 256
#define U_ 128
#define LDSW 264   // bf16 elems/row; 528B rows -> b128 frag reads hit the 8-cyc floor

typedef __attribute__((ext_vector_type(8))) short bf16x8;
typedef __attribute__((ext_vector_type(4))) float f32x4;

__device__ __forceinline__ short f2bf(float f) {
    unsigned u = __builtin_bit_cast(unsigned, f);
    u += 0x7fffu + ((u >> 16) & 1u);   // RTNE
    return (short)(u >> 16);
}

__device__ __forceinline__ float fast_tanh(float x) {
    float e = __expf(2.0f * x);        // v_exp_f32 path
    return 1.0f - 2.0f * __builtin_amdgcn_rcpf(e + 1.0f);
}

__device__ __forceinline__ bf16x8 cvt8(const float4& a, const float4& b) {
    union { __hip_bfloat162 h[4]; bf16x8 v; } u;
    u.h[0] = __float22bfloat162_rn(make_float2(a.x, a.y));
    u.h[1] = __float22bfloat162_rn(make_float2(a.z, a.w));
    u.h[2] = __float22bfloat162_rn(make_float2(b.x, b.y));
    u.h[3] = __float22bfloat162_rn(make_float2(b.z, b.w));
    return u.v;
}

__global__ __launch_bounds__(512)
__attribute__((amdgpu_waves_per_eu(4, 4)))
void additive_attn_kernel(
        const float* __restrict__ target,
        const float* __restrict__ source,
        const float* __restrict__ W1,
        const float* __restrict__ W2,
        const float* __restrict__ attn,
        float* __restrict__ out) {
    __shared__ __attribute__((aligned(16))) short lds_w2[U_ * LDSW]; // [u][d] bf16
    __shared__ float  lds_red[512];
    __shared__ float2 lds_sa[U_];   // {s_u, a_u}

    const int tid = threadIdx.x;
    const int bx  = blockIdx.x;
    const int b   = bx >> 3;            // 8 blocks per batch element
    const int tb  = (bx & 7) << 10;     // 1024 rows per block

    const int lane = tid & 63;
    const int wave = tid >> 6;   // 0..7
    const int c = lane & 15;
    const int g = lane >> 4;

    const float* tgt  = target + ((size_t)b * T_ + tb) * D_;
    float*       outp = out + (size_t)b * T_ + tb;
    const float* Abase = tgt + (size_t)(wave * 16 + c) * D_ + g * 8;

    // 3 payload sets (4 x float4 each): 48 VGPRs
    float4 p0, p1, p2, p3, q0, q1, q2, q3, r0, r1, r2, r3;

#define LOADB(X0, X1, X2, X3, BI) do {                                        \
    const float* p_ = Abase + (size_t)((BI) >> 2) * (128 * D_) + ((BI) & 3) * 64; \
    X0 = *(const float4*)(p_);      X1 = *(const float4*)(p_ + 4);            \
    X2 = *(const float4*)(p_ + 32); X3 = *(const float4*)(p_ + 36);           \
} while (0)

    // prime 2 batches before the prologue (8KB/wave in flight over staging)
    LOADB(p0, p1, p2, p3, 0);
    LOADB(q0, q1, q2, q3, 1);

    // --- stage W2: fp32 [D][U] -> bf16 LDS [u][d], b128 writes ---
    {
        const int u    = tid & (U_ - 1);
        const int dblk = (tid >> 7) << 6;    // 0,64,128,192
        #pragma unroll
        for (int w = 0; w < 8; ++w) {
            const int d0 = dblk + w * 8;
            bf16x8 v;
            #pragma unroll
            for (int i = 0; i < 8; ++i)
                v[i] = f2bf(W2[(size_t)(d0 + i) * U_ + u]);
            *(bf16x8*)&lds_w2[u * LDSW + d0] = v;
        }
    }

    // --- s[u] = (source[b] @ W1)[u], 4-way D split ---
    {
        const float* src = source + b * D_;
        const int u    = tid & (U_ - 1);
        const int part = tid >> 7;
        float acc = 0.f;
        #pragma unroll 8
        for (int d = part * 64; d < part * 64 + 64; ++d)
            acc = fmaf(src[d], W1[(size_t)d * U_ + u], acc);
        lds_red[tid] = acc;
    }
    __syncthreads();
    if (tid < U_)
        lds_sa[tid] = make_float2(
            lds_red[tid] + lds_red[tid + 128] + lds_red[tid + 256] + lds_red[tid + 384],
            attn[tid]);
    __syncthreads();

    f32x4 acc[8];
    #pragma unroll
    for (int j = 0; j < 8; ++j) acc[j] = (f32x4){0.f, 0.f, 0.f, 0.f};

    // swapped operands: A-op = W2 frag (m = u-in-tile), B-op = target (n = row c)
#define COMP(X0, X1, X2, X3, Q) do {                                          \
    bf16x8 af0 = cvt8(X0, X1);                                                \
    bf16x8 af1 = cvt8(X2, X3);                                                \
    const int kb_ = (Q) * 64 + g * 8;                                         \
    _Pragma("unroll")                                                         \
    for (int j = 0; j < 8; ++j) {                                             \
        bf16x8 w0 = *(const bf16x8*)&lds_w2[(16 * j + c) * LDSW + kb_];       \
        acc[j] = __builtin_amdgcn_mfma_f32_16x16x32_bf16(w0, af0, acc[j], 0, 0, 0); \
        bf16x8 w1 = *(const bf16x8*)&lds_w2[(16 * j + c) * LDSW + kb_ + 32];  \
        acc[j] = __builtin_amdgcn_mfma_f32_16x16x32_bf16(w1, af1, acc[j], 0, 0, 0); \
    }                                                                         \
} while (0)

    // lane (c,g) holds t[row][u=16j+4g+r] in acc[j][r]; row = rt*128+wave*16+c
#define EPI(IT) do {                                                          \
    float sc = 0.f;                                                           \
    _Pragma("unroll")                                                         \
    for (int j = 0; j < 8; ++j) {                                             \
        float4 sa01 = *(const float4*)&lds_sa[16 * j + 4 * g];                \
        float4 sa23 = *(const float4*)&lds_sa[16 * j + 4 * g + 2];            \
        sc += fast_tanh(acc[j][0] + sa01.x) * sa01.y;                         \
        sc += fast_tanh(acc[j][1] + sa01.z) * sa01.w;                         \
        sc += fast_tanh(acc[j][2] + sa23.x) * sa23.y;                         \
        sc += fast_tanh(acc[j][3] + sa23.z) * sa23.w;                         \
        acc[j] = (f32x4){0.f, 0.f, 0.f, 0.f};                                 \
    }                                                                         \
    sc += __shfl_xor(sc, 16);                                                 \
    sc += __shfl_xor(sc, 32);                                                 \
    if (lane < 16) outp[(IT) * 128 + wave * 16 + lane] = sc;                  \
} while (0)

    // 32 batches = 8 row-tiles x 4 k-quarters; 3-deep register pipeline.
    #pragma unroll
    for (int bi = 0; bi < 32; ++bi) {
        if (bi % 3 == 0) {
            if (bi < 30) LOADB(r0, r1, r2, r3, bi + 2);
            COMP(p0, p1, p2, p3, bi & 3);
        } else if (bi % 3 == 1) {
            if (bi < 30) LOADB(p0, p1, p2, p3, bi + 2);
            COMP(q0, q1, q2, q3, bi & 3);
        } else {
            if (bi < 30) LOADB(q0, q1, q2, q3, bi + 2);
            COMP(r0, r1, r2, r3, bi & 3);
        }
        if ((bi & 3) == 3) EPI(bi >> 2);
    }

#undef LOADB
#undef COMP
#undef EPI
}

extern "C" void kernel_launch(void* const* d_in, const int* in_sizes, int n_in,
                              void* d_out, int out_size, void* d_ws, size_t ws_size,
                              hipStream_t stream) {
    const float* target = (const float*)d_in[0];
    const float* source = (const float*)d_in[1];
    const float* W1     = (const float*)d_in[2];
    const float* W2     = (const float*)d_in[3];
    const float* attn   = (const float*)d_in[4];
    float* out = (float*)d_out;

    dim3 grid(B_ * (T_ / 1024));   // 512 blocks = 2 per CU, one dispatch round
    dim3 block(512);
    hipLaunchKernelGGL(additive_attn_kernel, grid, block, 0, stream,
                       target, source, W1, W2, attn, out);
}